// Round 22
// baseline (14195.389 us; speedup 1.0000x reference)
//
#include <hip/hip_runtime.h>
#include <math.h>

#define BATCH 8192
#define KB 2048      // num basis (N of fused GEMM)
#define DD 1024      // dim basis
#define LAM 0.1f
#define N_ITER 100
#define N_POWER 50

typedef unsigned short u16;
using short8 = __attribute__((ext_vector_type(8))) short;
using f32x4  = __attribute__((ext_vector_type(4))) float;

// ---------- bf16 split helpers (RNE) ----------
__device__ __forceinline__ u16 f2bf(float f) {
  unsigned int u = __builtin_bit_cast(unsigned int, f);
  u = u + 0x7FFFu + ((u >> 16) & 1u);
  return (u16)(u >> 16);
}
__device__ __forceinline__ float bf2f(u16 s) {
  unsigned int u = ((unsigned int)s) << 16;
  return __builtin_bit_cast(float, u);
}

// ---------- fp16 helpers (RNE via HW cvt) ----------
__device__ __forceinline__ u16 f2h(float f) {
  _Float16 h = (_Float16)f;
  return __builtin_bit_cast(unsigned short, h);
}
__device__ __forceinline__ float h2f(u16 s) {
  _Float16 h = __builtin_bit_cast(_Float16, s);
  return (float)h;
}

// ---------------- utility kernels ----------------
__global__ void k_split_f32(const float* __restrict__ in, u16* __restrict__ h,
                            u16* __restrict__ lo, int n) {  // bf16 pair
  for (int i = blockIdx.x * blockDim.x + threadIdx.x; i < n; i += gridDim.x * blockDim.x) {
    float v = in[i];
    u16 hh = f2bf(v);
    h[i] = hh;
    lo[i] = f2bf(v - bf2f(hh));
  }
}

// transposed bf16-pair split: th/tl[d][k] = split(phi[k][d])  (r3-proven)
__global__ __launch_bounds__(256) void k_split_phiT(const float* __restrict__ phi,
                                                    u16* __restrict__ th, u16* __restrict__ tl) {
  __shared__ float t[32][33];
  int k0 = blockIdx.y * 32, d0 = blockIdx.x * 32;
  int tx = threadIdx.x & 31, ty = threadIdx.x >> 5;  // 8 rows per pass
#pragma unroll
  for (int rr = 0; rr < 32; rr += 8)
    t[ty + rr][tx] = phi[(size_t)(k0 + ty + rr) * DD + d0 + tx];
  __syncthreads();
#pragma unroll
  for (int rr = 0; rr < 32; rr += 8) {
    float v = t[tx][ty + rr];  // = phi[k0+tx][d0+ty+rr]
    u16 hh = f2bf(v);
    size_t idx = (size_t)(d0 + ty + rr) * KB + (k0 + tx);
    th[idx] = hh;
    tl[idx] = f2bf(v - bf2f(hh));
  }
}

__global__ void k_cvt_f16(const float* __restrict__ in, u16* __restrict__ h, int n) {
  for (int i = blockIdx.x * blockDim.x + threadIdx.x; i < n; i += gridDim.x * blockDim.x)
    h[i] = f2h(in[i]);
}

// init power iteration: w = ones, partialA = 1/64 each (sum = 1 -> first norm = 1)
__global__ void k_init_pw(float* __restrict__ w, float* __restrict__ pA) {
  int i = blockIdx.x * 256 + threadIdx.x;
  if (i < KB) w[i] = 1.f;
  if (i < 64) pA[i] = 1.f / 64.f;
}

// ---------------- fused power step (r20-proven; ping-pong, no grid.sync) ----------------
template <int MODE>
__global__ __launch_bounds__(256) void k_power_fused(const float* __restrict__ G,
                                                     const float* __restrict__ win,
                                                     float* __restrict__ wout,
                                                     const float* __restrict__ pin,
                                                     float* __restrict__ pout) {
  int rloc = threadIdx.x >> 3;
  int seg = threadIdx.x & 7;
  int row = blockIdx.x * 32 + rloc;
  float n2 = 0.f;
#pragma unroll
  for (int i = 0; i < 64; ++i) n2 += pin[i];
  float n = sqrtf(n2);
  const float* g = G + (size_t)row * KB + seg * 256;
  const float* vv = win + seg * 256;
  float s = 0.f;
#pragma unroll 8
  for (int j = 0; j < 256; j += 4) {
    float4 gg = *(const float4*)(g + j);
    float4 vx = *(const float4*)(vv + j);
    s = fmaf(gg.x, vx.x, fmaf(gg.y, vx.y, fmaf(gg.z, vx.z, fmaf(gg.w, vx.w, s))));
  }
#pragma unroll
  for (int off = 1; off < 8; off <<= 1) s += __shfl_xor(s, off, 64);
  s = s / n;  // = row of G @ (win/||win||)
  float val;
  if (MODE == 0) {
    if (seg == 0) wout[row] = s;
    val = (seg == 0) ? s * s : 0.f;
  } else {
    val = (seg == 0) ? (win[row] / n) * s : 0.f;
  }
#pragma unroll
  for (int off = 8; off < 64; off <<= 1) val += __shfl_xor(val, off, 64);
  __shared__ float red[4];
  int lane = threadIdx.x & 63, wid = threadIdx.x >> 6;
  if (lane == 0) red[wid] = val;
  __syncthreads();
  if (threadIdx.x == 0) pout[blockIdx.x] = red[0] + red[1] + red[2] + red[3];
}

__global__ void k_compute_step(const float* __restrict__ partialL, float* __restrict__ stepbuf) {
  float L = 0.f;
#pragma unroll
  for (int i = 0; i < 64; ++i) L += partialL[i];
  stepbuf[0] = 1.f / L;
}

// ---------------- split-bf16 MFMA GEMM: C = A @ B^T (r3-proven body) ----------------
// EPI 0: out16[m*N+n] = fp16(acc)   (Cx)
// EPI 1: out32[m*N+n] = acc         (Gram fp32; also recon fp32)
template <int EPI>
__global__ __launch_bounds__(256) void k_xphiT(
    const u16* __restrict__ Ah, const u16* __restrict__ Al,
    const u16* __restrict__ Bh, const u16* __restrict__ Bl,
    u16* __restrict__ out16, float* __restrict__ out32, int N, int K) {
  __shared__ u16 lds[4 * 128 * 32];
  const int tid = threadIdx.x;
  const int w = tid >> 6, l = tid & 63;
  const int row0 = blockIdx.y * 128, col0 = blockIdx.x * 128;
  const int wm = (w >> 1) * 64, wn = (w & 1) * 64;
  const int lrow = l & 15, lk = (l >> 4) * 8;

  f32x4 zero4 = {0.f, 0.f, 0.f, 0.f};
  f32x4 acc[4][4];
#pragma unroll
  for (int i = 0; i < 4; ++i)
#pragma unroll
    for (int j = 0; j < 4; ++j) acc[i][j] = zero4;

  for (int k0 = 0; k0 < K; k0 += 32) {
    {
      const u16* gs[4] = {Ah, Al, Bh, Bl};
      const int r0s[4] = {row0, row0, col0, col0};
#pragma unroll
      for (int st = 0; st < 4; ++st) {
        u16* s = lds + st * 4096;
#pragma unroll
        for (int h = 0; h < 2; ++h) {
          int ch = h * 256 + w * 64 + l;
          const u16* gp = gs[st] + (size_t)(r0s[st] + (ch >> 2)) * K + k0 + (ch & 3) * 8;
          u16* sp = s + (h * 256 + w * 64) * 8;
          __builtin_amdgcn_global_load_lds((const __attribute__((address_space(1))) void*)gp,
                                           (__attribute__((address_space(3))) void*)sp, 16, 0, 0);
        }
      }
    }
    __syncthreads();
    short8 ah[4], al[4];
#pragma unroll
    for (int i = 0; i < 4; ++i) {
      int r = wm + i * 16 + lrow;
      ah[i] = *(const short8*)&lds[0 * 4096 + r * 32 + lk];
      al[i] = *(const short8*)&lds[1 * 4096 + r * 32 + lk];
    }
#pragma unroll
    for (int j = 0; j < 4; ++j) {
      int r = wn + j * 16 + lrow;
      short8 bh = *(const short8*)&lds[2 * 4096 + r * 32 + lk];
      short8 bl = *(const short8*)&lds[3 * 4096 + r * 32 + lk];
#pragma unroll
      for (int i = 0; i < 4; ++i) {
        acc[i][j] = __builtin_amdgcn_mfma_f32_16x16x32_bf16(ah[i], bh, acc[i][j], 0, 0, 0);
        acc[i][j] = __builtin_amdgcn_mfma_f32_16x16x32_bf16(ah[i], bl, acc[i][j], 0, 0, 0);
        acc[i][j] = __builtin_amdgcn_mfma_f32_16x16x32_bf16(al[i], bh, acc[i][j], 0, 0, 0);
      }
    }
    __syncthreads();
  }
#pragma unroll
  for (int i = 0; i < 4; ++i)
#pragma unroll
    for (int r = 0; r < 4; ++r) {
      int m = row0 + wm + i * 16 + ((l >> 4) << 2) + r;
      size_t base = (size_t)m * N;
#pragma unroll
      for (int j = 0; j < 4; ++j) {
        int n = col0 + wn + j * 16 + (l & 15);
        float v = acc[i][j][r];
        if (EPI == 0) {
          out16[base + n] = f2h(v);
        } else {
          out32[base + n] = v;
        }
      }
    }
}

// ---------------- iteration 0 (closed form: y=alpha=0, mu0=0; r20-proven) ----------------
__global__ void k_iter0(const u16* __restrict__ Cx, u16* __restrict__ Yout,
                        u16* __restrict__ Af16, const float* __restrict__ stepbuf) {
  const float step = stepbuf[0];
  const float thr = LAM * step;
  int n = BATCH * KB;
  for (int i = blockIdx.x * blockDim.x + threadIdx.x; i < n; i += gridDim.x * blockDim.x) {
    float z = step * h2f(Cx[i]);
    float az = fabsf(z) - thr;
    float a = az > 0.f ? copysignf(az, z) : 0.f;
    u16 ah = f2h(a);
    Af16[i] = ah;
    Yout[i] = ah;
  }
}

// ---------------- FISTA iteration: 128x128 tile, multi-block-per-CU ----------------
// r21 counters: the 128KB-LDS 256-block kernel is pinned at 1 block/CU - all
// barrier/stage stalls exposed (85us/iter vs 58us pipe-sum). k_xphiT (same
// round) at 32KB LDS runs 33% MfmaUtil via multi-block overlap (m114).
// This kernel = the r21 fista arithmetic in k_xphiT's proven geometry:
// 256 thr / 4 waves, BK=32 single-buffered 16KB LDS, 1024 blocks (~4/CU).
// Accumulation chain identical (64 sequential K=32 MFMA) -> same absmax.
// T1 bijection: lin = (by>>3)<<7 | bx<<3 | (by&7), so lin%8 == by%8 (panel
// readers share an XCD; per-XCD panel footprint 8x0.5MB = 4MB = L2 size).

__global__ __launch_bounds__(256) void k_fista_fused(
    const u16* __restrict__ Yin, u16* __restrict__ Yout, u16* Af16,
    const u16* __restrict__ Gh,
    const u16* __restrict__ Cx, float* AlphaOut,
    const float* __restrict__ stepbuf, float mu, int last) {
  __shared__ u16 lds[2 * 128 * 32];  // A 4096 u16 | B 4096 u16 = 16 KB

  const int tid = threadIdx.x;
  const int w = tid >> 6, l = tid & 63;
  const int wm = (w >> 1) * 64, wn = (w & 1) * 64;
  const int lrow = l & 15, lk = (l >> 4) * 8;

  const int lin = blockIdx.x;                  // [0,1024)
  const int by = ((lin >> 7) << 3) + (lin & 7);  // [0,64)
  const int bx = (lin >> 3) & 15;                // [0,16)
  const int row0 = by * 128, col0 = bx * 128;

  f32x4 zero4 = {0.f, 0.f, 0.f, 0.f};
  f32x4 acc[4][4];
#pragma unroll
  for (int i = 0; i < 4; ++i)
#pragma unroll
    for (int j = 0; j < 4; ++j) acc[i][j] = zero4;

  for (int k0 = 0; k0 < KB; k0 += 32) {
    {
      const u16* gs[2] = {Yin, Gh};
      const int r0s[2] = {row0, col0};
#pragma unroll
      for (int st = 0; st < 2; ++st) {
        u16* s = lds + st * 4096;
#pragma unroll
        for (int h = 0; h < 2; ++h) {
          int ch = h * 256 + w * 64 + l;
          const u16* gp = gs[st] + (size_t)(r0s[st] + (ch >> 2)) * KB + k0 + (ch & 3) * 8;
          u16* sp = s + (h * 256 + w * 64) * 8;
          __builtin_amdgcn_global_load_lds((const __attribute__((address_space(1))) void*)gp,
                                           (__attribute__((address_space(3))) void*)sp, 16, 0, 0);
        }
      }
    }
    __syncthreads();
    short8 af[4], bf[4];
#pragma unroll
    for (int i = 0; i < 4; ++i) {
      int r = wm + i * 16 + lrow;
      af[i] = *(const short8*)&lds[0 * 4096 + r * 32 + lk];
    }
#pragma unroll
    for (int j = 0; j < 4; ++j) {
      int r = wn + j * 16 + lrow;
      bf[j] = *(const short8*)&lds[1 * 4096 + r * 32 + lk];
    }
    __builtin_amdgcn_s_setprio(1);
#pragma unroll
    for (int i = 0; i < 4; ++i)
#pragma unroll
      for (int j = 0; j < 4; ++j)
        acc[i][j] = __builtin_amdgcn_mfma_f32_16x16x32_f16(af[i], bf[j], acc[i][j], 0, 0, 0);
    __builtin_amdgcn_s_setprio(0);
    __syncthreads();
  }

  // ---- epilogue (tile-local; Yout != Yin so no device-wide sync needed) ----
  const float step = stepbuf[0];
  const float thr = LAM * step;
#pragma unroll
  for (int i = 0; i < 4; ++i) {
#pragma unroll
    for (int r = 0; r < 4; ++r) {
      int m = row0 + wm + i * 16 + ((l >> 4) << 2) + r;
      size_t base = (size_t)m * KB;
#pragma unroll
      for (int j = 0; j < 4; ++j) {
        int n = col0 + wn + j * 16 + (l & 15);
        size_t idx = base + n;
        float g = acc[i][j][r] - h2f(Cx[idx]);
        float y = h2f(Yin[idx]);
        float z = y - step * g;
        float az = fabsf(z) - thr;
        float a = az > 0.f ? copysignf(az, z) : 0.f;
        float ap = h2f(Af16[idx]);
        float yn = a + mu * (a - ap);
        Af16[idx] = f2h(a);
        if (last) AlphaOut[idx] = a;
        Yout[idx] = f2h(yn);
      }
    }
  }
}

// ---------------- launch ----------------
extern "C" void kernel_launch(void* const* d_in, const int* in_sizes, int n_in,
                              void* d_out, int out_size, void* d_ws, size_t ws_size,
                              hipStream_t stream) {
  const float* x = (const float*)d_in[0];    // [8192,1024]
  const float* phi = (const float*)d_in[1];  // [2048,1024]
  float* out = (float*)d_out;
  float* alpha = out;                             // [8192*2048] fp32, written at last iter
  float* reconF = out + (size_t)BATCH * KB;       // [8192*1024] fp32 (33.55 MB scratch region)

  // ---- workspace layout (byte offsets) ----
  char* ws = (char*)d_ws;
  u16* YA = (u16*)ws;                                   // 33,554,432 B (fp16 y buffer A)
  u16* Af16 = (u16*)(ws + 33554432ull);                 // 33,554,432 B (fp16 alpha history)
  u16* Gph = (u16*)(ws + 67108864ull);                  // 8,388,608 B  (Gh fp16; temp phiH bf16)
  u16* Gpl = (u16*)(ws + 75497472ull);                  // 8,388,608 B  (temp phiL bf16)
  u16* Cx16 = (u16*)(ws + 83886080ull);                 // 33,554,432 B (fp16 Cx)
  float* Gf = (float*)(ws + 117440512ull);              // 16,777,216 B (fp32 G; later phiT splits)
  float* stepbuf = (float*)(ws + 150994944ull);         // 64 B
  const size_t need = 150995008ull;
  if (ws_size < need) return;

  // Y buffer B lives in the recon region of d_out (dead until final recon).
  u16* YB = (u16*)reconF;                               // 33,554,432 B (fp16 y buffer B)

  // pre-FISTA temporaries in recon region of d_out (dead before k_iter0):
  u16* xh = (u16*)reconF;           // x split hi [8192*1024]
  u16* xl = xh + (size_t)BATCH * DD;
  float* vA = reconF;               // power-iter ping-pong (xh/xl dead after Cx)
  float* vB = reconF + 2048;
  float* pA = reconF + 4096;        // 64 floats
  float* pB = reconF + 4224;        // 64 floats

  // 1. splits: phi -> (Gph,Gpl temp, bf16 pair), x -> (xh,xl)
  k_split_f32<<<2048, 256, 0, stream>>>(phi, Gph, Gpl, KB * DD);
  k_split_f32<<<2048, 256, 0, stream>>>(x, xh, xl, BATCH * DD);

  // 2. Cx = x @ phi^T (fp16 out), M=8192 N=2048 K=1024
  k_xphiT<0><<<dim3(KB / 128, BATCH / 128), 256, 0, stream>>>(
      xh, xl, Gph, Gpl, Cx16, nullptr, KB, DD);

  // 3. G = phi @ phi^T (fp32 out via MFMA), M=N=2048 K=1024
  k_xphiT<1><<<dim3(KB / 128, KB / 128), 256, 0, stream>>>(
      Gph, Gpl, Gph, Gpl, nullptr, Gf, KB, DD);

  // 4. power iteration: 50 fused steps (ping-pong) + Rayleigh + step (r20-proven)
  k_init_pw<<<8, 256, 0, stream>>>(vA, pA);
  for (int s = 0; s < N_POWER; ++s) {
    const float* win = (s & 1) ? vB : vA;
    float* wout = (s & 1) ? vA : vB;
    const float* pin = (s & 1) ? pB : pA;
    float* pout = (s & 1) ? pA : pB;
    k_power_fused<0><<<64, 256, 0, stream>>>(Gf, win, wout, pin, pout);
  }
  k_power_fused<1><<<64, 256, 0, stream>>>(Gf, vA, nullptr, pA, pB);
  k_compute_step<<<1, 1, 0, stream>>>(pB, stepbuf);

  // 5. Gh = fp16(G) (overwrites phiH split; dead after steps 2-3)
  k_cvt_f16<<<2048, 256, 0, stream>>>(Gf, Gph, KB * KB);

  // 6. iteration 0 closed-form -> Y into YA
  k_iter0<<<2048, 256, 0, stream>>>(Cx16, YA, Af16, stepbuf);

  // 7. FISTA iterations 1..99: plain launches, Y ping-pong, 1024 blocks
  float t = 1.f;
  float mus[N_ITER];
  for (int it = 0; it < N_ITER; ++it) {
    float tn = 0.5f * (1.f + sqrtf(1.f + 4.f * t * t));
    mus[it] = (t - 1.f) / tn;
    t = tn;
  }
  u16* ycur = YA;  // holds y_1 (written by iter 0)
  u16* ynext = YB;
  for (int it = 1; it < N_ITER; ++it) {
    int last = (it == N_ITER - 1) ? 1 : 0;
    k_fista_fused<<<dim3(1024), 256, 0, stream>>>(
        ycur, ynext, Af16, Gph, Cx16, alpha, stepbuf, mus[it], last);
    u16* tmp = ycur; ycur = ynext; ynext = tmp;
  }

  // 8. recon = alpha @ phi via split-bf16 MFMA (alpha splits into dead YA/Af16;
  //    phi^T splits into dead Gf region; recon overwrites YB region afterwards)
  u16* aH = YA;                       // bf16 alpha hi
  u16* aL = Af16;                     // bf16 alpha lo
  u16* pTh = (u16*)Gf;                // bf16 phiT hi [DD][KB]
  u16* pTl = pTh + (size_t)DD * KB;   // bf16 phiT lo
  k_split_f32<<<2048, 256, 0, stream>>>(alpha, aH, aL, BATCH * KB);
  k_split_phiT<<<dim3(DD / 32, KB / 32), 256, 0, stream>>>(phi, pTh, pTl);
  k_xphiT<1><<<dim3(DD / 128, BATCH / 128), 256, 0, stream>>>(
      aH, aL, pTh, pTl, nullptr, reconF, DD, KB);
}

// Round 23
// 10000.442 us; speedup vs baseline: 1.4195x; 1.4195x over previous
//
#include <hip/hip_runtime.h>
#include <math.h>

#define BATCH 8192
#define KB 2048      // num basis (N of fused GEMM)
#define DD 1024      // dim basis
#define LAM 0.1f
#define N_ITER 100
#define N_POWER 50
#define NTILES 32    // K' = 2048 = 32 * 64  (fp16 1-term: yh vs Gh)

typedef unsigned short u16;
using short8 = __attribute__((ext_vector_type(8))) short;
using f32x4  = __attribute__((ext_vector_type(4))) float;

// ---------- bf16 split helpers (RNE) ----------
__device__ __forceinline__ u16 f2bf(float f) {
  unsigned int u = __builtin_bit_cast(unsigned int, f);
  u = u + 0x7FFFu + ((u >> 16) & 1u);
  return (u16)(u >> 16);
}
__device__ __forceinline__ float bf2f(u16 s) {
  unsigned int u = ((unsigned int)s) << 16;
  return __builtin_bit_cast(float, u);
}

// ---------- fp16 helpers (RNE via HW cvt) ----------
__device__ __forceinline__ u16 f2h(float f) {
  _Float16 h = (_Float16)f;
  return __builtin_bit_cast(unsigned short, h);
}
__device__ __forceinline__ float h2f(u16 s) {
  _Float16 h = __builtin_bit_cast(_Float16, s);
  return (float)h;
}

// ---------------- utility kernels ----------------
__global__ void k_split_f32(const float* __restrict__ in, u16* __restrict__ h,
                            u16* __restrict__ lo, int n) {  // bf16 pair
  for (int i = blockIdx.x * blockDim.x + threadIdx.x; i < n; i += gridDim.x * blockDim.x) {
    float v = in[i];
    u16 hh = f2bf(v);
    h[i] = hh;
    lo[i] = f2bf(v - bf2f(hh));
  }
}

// transposed bf16-pair split: th/tl[d][k] = split(phi[k][d])  (r3-proven)
__global__ __launch_bounds__(256) void k_split_phiT(const float* __restrict__ phi,
                                                    u16* __restrict__ th, u16* __restrict__ tl) {
  __shared__ float t[32][33];
  int k0 = blockIdx.y * 32, d0 = blockIdx.x * 32;
  int tx = threadIdx.x & 31, ty = threadIdx.x >> 5;  // 8 rows per pass
#pragma unroll
  for (int rr = 0; rr < 32; rr += 8)
    t[ty + rr][tx] = phi[(size_t)(k0 + ty + rr) * DD + d0 + tx];
  __syncthreads();
#pragma unroll
  for (int rr = 0; rr < 32; rr += 8) {
    float v = t[tx][ty + rr];  // = phi[k0+tx][d0+ty+rr]
    u16 hh = f2bf(v);
    size_t idx = (size_t)(d0 + ty + rr) * KB + (k0 + tx);
    th[idx] = hh;
    tl[idx] = f2bf(v - bf2f(hh));
  }
}

__global__ void k_cvt_f16(const float* __restrict__ in, u16* __restrict__ h, int n) {
  for (int i = blockIdx.x * blockDim.x + threadIdx.x; i < n; i += gridDim.x * blockDim.x)
    h[i] = f2h(in[i]);
}

// init power iteration: w = ones, partialA = 1/64 each (sum = 1 -> first norm = 1)
__global__ void k_init_pw(float* __restrict__ w, float* __restrict__ pA) {
  int i = blockIdx.x * 256 + threadIdx.x;
  if (i < KB) w[i] = 1.f;
  if (i < 64) pA[i] = 1.f / 64.f;
}

// ---------------- fused power step (r20-proven; ping-pong, no grid.sync) ----------------
template <int MODE>
__global__ __launch_bounds__(256) void k_power_fused(const float* __restrict__ G,
                                                     const float* __restrict__ win,
                                                     float* __restrict__ wout,
                                                     const float* __restrict__ pin,
                                                     float* __restrict__ pout) {
  int rloc = threadIdx.x >> 3;
  int seg = threadIdx.x & 7;
  int row = blockIdx.x * 32 + rloc;
  float n2 = 0.f;
#pragma unroll
  for (int i = 0; i < 64; ++i) n2 += pin[i];
  float n = sqrtf(n2);
  const float* g = G + (size_t)row * KB + seg * 256;
  const float* vv = win + seg * 256;
  float s = 0.f;
#pragma unroll 8
  for (int j = 0; j < 256; j += 4) {
    float4 gg = *(const float4*)(g + j);
    float4 vx = *(const float4*)(vv + j);
    s = fmaf(gg.x, vx.x, fmaf(gg.y, vx.y, fmaf(gg.z, vx.z, fmaf(gg.w, vx.w, s))));
  }
#pragma unroll
  for (int off = 1; off < 8; off <<= 1) s += __shfl_xor(s, off, 64);
  s = s / n;  // = row of G @ (win/||win||)
  float val;
  if (MODE == 0) {
    if (seg == 0) wout[row] = s;
    val = (seg == 0) ? s * s : 0.f;
  } else {
    val = (seg == 0) ? (win[row] / n) * s : 0.f;
  }
#pragma unroll
  for (int off = 8; off < 64; off <<= 1) val += __shfl_xor(val, off, 64);
  __shared__ float red[4];
  int lane = threadIdx.x & 63, wid = threadIdx.x >> 6;
  if (lane == 0) red[wid] = val;
  __syncthreads();
  if (threadIdx.x == 0) pout[blockIdx.x] = red[0] + red[1] + red[2] + red[3];
}

__global__ void k_compute_step(const float* __restrict__ partialL, float* __restrict__ stepbuf) {
  float L = 0.f;
#pragma unroll
  for (int i = 0; i < 64; ++i) L += partialL[i];
  stepbuf[0] = 1.f / L;
}

// ---------------- split-bf16 MFMA GEMM: C = A @ B^T (r3-proven body) ----------------
// EPI 0: out16[m*N+n] = fp16(acc)   (Cx)
// EPI 1: out32[m*N+n] = acc         (Gram fp32; also recon fp32)
template <int EPI>
__global__ __launch_bounds__(256) void k_xphiT(
    const u16* __restrict__ Ah, const u16* __restrict__ Al,
    const u16* __restrict__ Bh, const u16* __restrict__ Bl,
    u16* __restrict__ out16, float* __restrict__ out32, int N, int K) {
  __shared__ u16 lds[4 * 128 * 32];
  const int tid = threadIdx.x;
  const int w = tid >> 6, l = tid & 63;
  const int row0 = blockIdx.y * 128, col0 = blockIdx.x * 128;
  const int wm = (w >> 1) * 64, wn = (w & 1) * 64;
  const int lrow = l & 15, lk = (l >> 4) * 8;

  f32x4 zero4 = {0.f, 0.f, 0.f, 0.f};
  f32x4 acc[4][4];
#pragma unroll
  for (int i = 0; i < 4; ++i)
#pragma unroll
    for (int j = 0; j < 4; ++j) acc[i][j] = zero4;

  for (int k0 = 0; k0 < K; k0 += 32) {
    {
      const u16* gs[4] = {Ah, Al, Bh, Bl};
      const int r0s[4] = {row0, row0, col0, col0};
#pragma unroll
      for (int st = 0; st < 4; ++st) {
        u16* s = lds + st * 4096;
#pragma unroll
        for (int h = 0; h < 2; ++h) {
          int ch = h * 256 + w * 64 + l;
          const u16* gp = gs[st] + (size_t)(r0s[st] + (ch >> 2)) * K + k0 + (ch & 3) * 8;
          u16* sp = s + (h * 256 + w * 64) * 8;
          __builtin_amdgcn_global_load_lds((const __attribute__((address_space(1))) void*)gp,
                                           (__attribute__((address_space(3))) void*)sp, 16, 0, 0);
        }
      }
    }
    __syncthreads();
    short8 ah[4], al[4];
#pragma unroll
    for (int i = 0; i < 4; ++i) {
      int r = wm + i * 16 + lrow;
      ah[i] = *(const short8*)&lds[0 * 4096 + r * 32 + lk];
      al[i] = *(const short8*)&lds[1 * 4096 + r * 32 + lk];
    }
#pragma unroll
    for (int j = 0; j < 4; ++j) {
      int r = wn + j * 16 + lrow;
      short8 bh = *(const short8*)&lds[2 * 4096 + r * 32 + lk];
      short8 bl = *(const short8*)&lds[3 * 4096 + r * 32 + lk];
#pragma unroll
      for (int i = 0; i < 4; ++i) {
        acc[i][j] = __builtin_amdgcn_mfma_f32_16x16x32_bf16(ah[i], bh, acc[i][j], 0, 0, 0);
        acc[i][j] = __builtin_amdgcn_mfma_f32_16x16x32_bf16(ah[i], bl, acc[i][j], 0, 0, 0);
        acc[i][j] = __builtin_amdgcn_mfma_f32_16x16x32_bf16(al[i], bh, acc[i][j], 0, 0, 0);
      }
    }
    __syncthreads();
  }
#pragma unroll
  for (int i = 0; i < 4; ++i)
#pragma unroll
    for (int r = 0; r < 4; ++r) {
      int m = row0 + wm + i * 16 + ((l >> 4) << 2) + r;
      size_t base = (size_t)m * N;
#pragma unroll
      for (int j = 0; j < 4; ++j) {
        int n = col0 + wn + j * 16 + (l & 15);
        float v = acc[i][j][r];
        if (EPI == 0) {
          out16[base + n] = f2h(v);
        } else {
          out32[base + n] = v;
        }
      }
    }
}

// ---------------- iteration 0 (closed form: y=alpha=0, mu0=0; r20-proven) ----------------
__global__ void k_iter0(const u16* __restrict__ Cx, u16* __restrict__ Yout,
                        u16* __restrict__ Af16, const float* __restrict__ stepbuf) {
  const float step = stepbuf[0];
  const float thr = LAM * step;
  int n = BATCH * KB;
  for (int i = blockIdx.x * blockDim.x + threadIdx.x; i < n; i += gridDim.x * blockDim.x) {
    float z = step * h2f(Cx[i]);
    float az = fabsf(z) - thr;
    float a = az > 0.f ? copysignf(az, z) : 0.f;
    u16 ah = f2h(a);
    Af16[i] = ah;
    Yout[i] = ah;
  }
}

// ---------------- FISTA iteration (r21-proven 10.00ms: 256^2 swizzled, Y ping-pong) ----
// r22 post-mortem: 128^2 multi-block port regressed 42% (8.4M bank conflicts
// from the unswizzled LDS layout + 64 single-buffered tiles x 2 barriers).
// Occupancy does not substitute for conflict-free stage-ahead. This kernel
// (XOR swizzle: 0 conflicts; 1 barrier/tile; stage-first 1-tile-ahead;
// no device-wide sync via Y_in/Y_out split) is the proven optimum.

__device__ __forceinline__ void stage_op(const u16* src, int r0, int q0,
                                         u16* ldsbase, int tid) {
#pragma unroll
  for (int i = 0; i < 4; ++i) {
    int c = i * 512 + tid;
    int r = c >> 3;
    int sp = (c & 7) ^ (r & 7);
    const u16* gp = src + ((size_t)(r0 + r) << 11) + (q0 + (sp << 3));
    u16* lp = ldsbase + ((i * 512 + (tid & 448)) << 3);  // wave-uniform base
    __builtin_amdgcn_global_load_lds((const __attribute__((address_space(1))) void*)gp,
                                     (__attribute__((address_space(3))) void*)lp, 16, 0, 0);
  }
}

__global__ __launch_bounds__(512, 1) void k_fista_fused(
    const u16* __restrict__ Yin, u16* __restrict__ Yout, u16* Af16,
    const u16* __restrict__ Gh,
    const u16* __restrict__ Cx, float* AlphaOut,
    const float* __restrict__ stepbuf, float mu, int last) {
  __shared__ u16 lds[65536];  // 128 KB static: [buf][A 16384 u16 | B 16384 u16]

  const int tid = threadIdx.x;
  const int w = tid >> 6, l = tid & 63;
  const int wm = w >> 2, wn = w & 3;       // 2 x 4 waves
  const int lr = l & 15, lg = l >> 4;

  // XCD-aware remap (r9-verified: FETCH 595->332 MB/iter).
  const int lin = blockIdx.x + (int)gridDim.x * blockIdx.y;  // [0,256)
  const int bq = lin >> 6;          // [0,4)
  const int bp = (lin >> 3) & 7;    // [0,8)
  const int br = lin & 7;           // [0,8)
  const int row0 = ((bq << 3) + br) * 256;  // by = 8q + r
  const int col0 = bp * 256;                // bx = p

  f32x4 acc[8][4];
  f32x4 zero4 = {0.f, 0.f, 0.f, 0.f};
#pragma unroll
  for (int i = 0; i < 8; ++i)
#pragma unroll
    for (int j = 0; j < 4; ++j) acc[i][j] = zero4;

  // prologue: stage tile 0 into buf0 only (1-tile-ahead scheme)
  stage_op(Yin, row0, 0, lds, tid);
  stage_op(Gh, col0, 0, lds + 16384, tid);

#define FBODY(TT, B)                                                              \
  {                                                                               \
    asm volatile("s_waitcnt vmcnt(0)" ::: "memory");                              \
    __builtin_amdgcn_s_barrier();                                                 \
    __builtin_amdgcn_sched_barrier(0);                                            \
    {                                                                             \
      int tn = (TT) + 1;                                                          \
      if (tn >= NTILES) tn = 0;                                                   \
      int q0 = tn << 6;                                                           \
      stage_op(Yin, row0, q0, lds + ((B) ? 0 : 32768), tid);                      \
      stage_op(Gh, col0, q0, lds + ((B) ? 0 : 32768) + 16384, tid);               \
    }                                                                             \
    __builtin_amdgcn_sched_barrier(0);                                            \
    const u16* baseA = lds + ((B) ? 32768 : 0);                                   \
    const u16* baseB = baseA + 16384;                                             \
    short8 bf[4][2];                                                              \
    _Pragma("unroll") for (int j = 0; j < 4; ++j) {                               \
      _Pragma("unroll") for (int ks = 0; ks < 2; ++ks) {                          \
        int brow = wn * 64 + j * 16 + lr;                                         \
        int slot = ks * 4 + lg;                                                   \
        bf[j][ks] = *(const short8*)(baseB + brow * 64 + ((slot ^ (brow & 7)) << 3)); \
      }                                                                           \
    }                                                                             \
    __builtin_amdgcn_s_setprio(1);                                                \
    _Pragma("unroll") for (int i = 0; i < 8; ++i) {                               \
      int arow = wm * 128 + i * 16 + lr;                                          \
      short8 a0 = *(const short8*)(baseA + arow * 64 + (((0 + lg) ^ (arow & 7)) << 3)); \
      short8 a1 = *(const short8*)(baseA + arow * 64 + (((4 + lg) ^ (arow & 7)) << 3)); \
      _Pragma("unroll") for (int j = 0; j < 4; ++j) {                             \
        acc[i][j] = __builtin_amdgcn_mfma_f32_16x16x32_f16(a0, bf[j][0], acc[i][j], 0, 0, 0); \
        acc[i][j] = __builtin_amdgcn_mfma_f32_16x16x32_f16(a1, bf[j][1], acc[i][j], 0, 0, 0); \
      }                                                                           \
    }                                                                             \
    __builtin_amdgcn_s_setprio(0);                                                \
  }

  for (int tt = 0; tt < NTILES; tt += 2) {
    FBODY(tt, 0)
    FBODY(tt + 1, 1)
  }
#undef FBODY

  // ---- epilogue (no device-wide sync needed: Yout != Yin, Af16 tile-local) ----
  const float step = stepbuf[0];
  const float thr = LAM * step;
#pragma unroll
  for (int i = 0; i < 8; ++i) {
#pragma unroll
    for (int r = 0; r < 4; ++r) {
      int m = row0 + wm * 128 + i * 16 + (lg << 2) + r;
      size_t base = (size_t)m * KB;
#pragma unroll
      for (int j = 0; j < 4; ++j) {
        int n = col0 + wn * 64 + j * 16 + lr;
        size_t idx = base + n;
        float g = acc[i][j][r] - h2f(Cx[idx]);
        float y = h2f(Yin[idx]);
        float z = y - step * g;
        float az = fabsf(z) - thr;
        float a = az > 0.f ? copysignf(az, z) : 0.f;
        float ap = h2f(Af16[idx]);
        float yn = a + mu * (a - ap);
        Af16[idx] = f2h(a);
        if (last) AlphaOut[idx] = a;
        Yout[idx] = f2h(yn);
      }
    }
  }
}

// ---------------- launch ----------------
extern "C" void kernel_launch(void* const* d_in, const int* in_sizes, int n_in,
                              void* d_out, int out_size, void* d_ws, size_t ws_size,
                              hipStream_t stream) {
  const float* x = (const float*)d_in[0];    // [8192,1024]
  const float* phi = (const float*)d_in[1];  // [2048,1024]
  float* out = (float*)d_out;
  float* alpha = out;                             // [8192*2048] fp32, written at last iter
  float* reconF = out + (size_t)BATCH * KB;       // [8192*1024] fp32 (33.55 MB scratch region)

  // ---- workspace layout (byte offsets) ----
  char* ws = (char*)d_ws;
  u16* YA = (u16*)ws;                                   // 33,554,432 B (fp16 y buffer A)
  u16* Af16 = (u16*)(ws + 33554432ull);                 // 33,554,432 B (fp16 alpha history)
  u16* Gph = (u16*)(ws + 67108864ull);                  // 8,388,608 B  (Gh fp16; temp phiH bf16)
  u16* Gpl = (u16*)(ws + 75497472ull);                  // 8,388,608 B  (temp phiL bf16)
  u16* Cx16 = (u16*)(ws + 83886080ull);                 // 33,554,432 B (fp16 Cx)
  float* Gf = (float*)(ws + 117440512ull);              // 16,777,216 B (fp32 G; later phiT splits)
  float* stepbuf = (float*)(ws + 150994944ull);         // 64 B
  const size_t need = 150995008ull;
  if (ws_size < need) return;

  // Y buffer B lives in the recon region of d_out (dead until final recon).
  u16* YB = (u16*)reconF;                               // 33,554,432 B (fp16 y buffer B)

  // pre-FISTA temporaries in recon region of d_out (dead before k_iter0):
  u16* xh = (u16*)reconF;           // x split hi [8192*1024]
  u16* xl = xh + (size_t)BATCH * DD;
  float* vA = reconF;               // power-iter ping-pong (xh/xl dead after Cx)
  float* vB = reconF + 2048;
  float* pA = reconF + 4096;        // 64 floats
  float* pB = reconF + 4224;        // 64 floats

  // 1. splits: phi -> (Gph,Gpl temp, bf16 pair), x -> (xh,xl)
  k_split_f32<<<2048, 256, 0, stream>>>(phi, Gph, Gpl, KB * DD);
  k_split_f32<<<2048, 256, 0, stream>>>(x, xh, xl, BATCH * DD);

  // 2. Cx = x @ phi^T (fp16 out), M=8192 N=2048 K=1024
  k_xphiT<0><<<dim3(KB / 128, BATCH / 128), 256, 0, stream>>>(
      xh, xl, Gph, Gpl, Cx16, nullptr, KB, DD);

  // 3. G = phi @ phi^T (fp32 out via MFMA), M=N=2048 K=1024
  k_xphiT<1><<<dim3(KB / 128, KB / 128), 256, 0, stream>>>(
      Gph, Gpl, Gph, Gpl, nullptr, Gf, KB, DD);

  // 4. power iteration: 50 fused steps (ping-pong) + Rayleigh + step (r20-proven)
  k_init_pw<<<8, 256, 0, stream>>>(vA, pA);
  for (int s = 0; s < N_POWER; ++s) {
    const float* win = (s & 1) ? vB : vA;
    float* wout = (s & 1) ? vA : vB;
    const float* pin = (s & 1) ? pB : pA;
    float* pout = (s & 1) ? pA : pB;
    k_power_fused<0><<<64, 256, 0, stream>>>(Gf, win, wout, pin, pout);
  }
  k_power_fused<1><<<64, 256, 0, stream>>>(Gf, vA, nullptr, pA, pB);
  k_compute_step<<<1, 1, 0, stream>>>(pB, stepbuf);

  // 5. Gh = fp16(G) (overwrites phiH split; dead after steps 2-3)
  k_cvt_f16<<<2048, 256, 0, stream>>>(Gf, Gph, KB * KB);

  // 6. iteration 0 closed-form -> Y into YA
  k_iter0<<<2048, 256, 0, stream>>>(Cx16, YA, Af16, stepbuf);

  // 7. FISTA iterations 1..99: plain launches, Y ping-pong (no grid.sync anywhere)
  float t = 1.f;
  float mus[N_ITER];
  for (int it = 0; it < N_ITER; ++it) {
    float tn = 0.5f * (1.f + sqrtf(1.f + 4.f * t * t));
    mus[it] = (t - 1.f) / tn;
    t = tn;
  }
  u16* ycur = YA;  // holds y_1 (written by iter 0)
  u16* ynext = YB;
  for (int it = 1; it < N_ITER; ++it) {
    int last = (it == N_ITER - 1) ? 1 : 0;
    k_fista_fused<<<dim3(KB / 256, BATCH / 256), 512, 0, stream>>>(
        ycur, ynext, Af16, Gph, Cx16, alpha, stepbuf, mus[it], last);
    u16* tmp = ycur; ycur = ynext; ynext = tmp;
  }

  // 8. recon = alpha @ phi via split-bf16 MFMA (alpha splits into dead YA/Af16;
  //    phi^T splits into dead Gf region; recon overwrites YB region afterwards)
  u16* aH = YA;                       // bf16 alpha hi
  u16* aL = Af16;                     // bf16 alpha lo
  u16* pTh = (u16*)Gf;                // bf16 phiT hi [DD][KB]
  u16* pTl = pTh + (size_t)DD * KB;   // bf16 phiT lo
  k_split_f32<<<2048, 256, 0, stream>>>(alpha, aH, aL, BATCH * KB);
  k_split_phiT<<<dim3(DD / 32, KB / 32), 256, 0, stream>>>(phi, pTh, pTl);
  k_xphiT<1><<<dim3(DD / 128, BATCH / 128), 256, 0, stream>>>(
      aH, aL, pTh, pTl, nullptr, reconF, DD, KB);
}